// Round 3
// baseline (325.063 us; speedup 1.0000x reference)
//
#include <hip/hip_runtime.h>
#include <hip/hip_bf16.h>
#include <stdint.h>

#define N_NODES 100000
#define N_EDGES 6400000

#define NPB 128                                   // dst nodes per bucket
#define NBKT 782                                  // ceil(100000/128)
#define CAP 10752                                 // records/bucket stride
#define SORT_CAP 9216                             // per-bucket clamp (mean 8184, sigma~90, proven max ~8.5k)
#define OUT_CAP (SORT_CAP + NPB * 3)              // 9600: staging incl. 4-align padding
#define BIN_CHUNK 4096                            // halved: 8 recs/thread, no spills
#define BIN_THREADS 512
#define BIN_ITER (BIN_CHUNK / BIN_THREADS)        // 8
#define SORT_THREADS 512
#define SORT_V4 5                                 // uint4 rounds: covers SORT_CAP
#define NBIN_BLOCKS ((N_EDGES + BIN_CHUNK - 1) / BIN_CHUNK)  // 1563

// perm1 record: src (bits 0..16) | dstLocal (bits 17..23) | bktLow8 (bits 24..31)
//   src < 100000 < 0x1FFFF  =>  a valid record can never equal 0xFFFFFFFF
// perm2: src only, dst-sorted, segments 4-aligned (holes never read)

__device__ __forceinline__ void make_rec(unsigned s, unsigned d,
                                         unsigned& rec, int& pk) {
  if (s < N_NODES && d < N_NODES) {
    pk = (int)(d >> 7);                            // bucket in low 16
    rec = s | ((d & (NPB - 1u)) << 17) | (((d >> 7) & 255u) << 24);
  }
}

// ---------------------------------------------------------------------------
// Bin edges by dst bucket. 8 records/thread: rec[8] + packed pk[8]
// (bucket | rank<<16) = ~16 state VGPRs -> no scratch spills at the
// launch_bounds(512,8)-pinned 64-VGPR budget. LDS 20.5KB; occupancy cap is
// the 32-wave limit (4 blocks/CU).
__global__ __launch_bounds__(512, 8) void k_bin(const void* __restrict__ ei,
                                                int* __restrict__ gcur,
                                                unsigned* __restrict__ perm1) {
  __shared__ unsigned staging[BIN_CHUNK];          // 16 KB
  __shared__ int lcnt[1024];                       // counts -> excl -> combo
  __shared__ int wsum[8];
  __shared__ int s_tot;
  __shared__ int s_th[3];
  __shared__ int s_is64;
  int t = threadIdx.x;
  lcnt[t] = 0; lcnt[t + 512] = 0;
  if (t < 64) {
    unsigned hv = ((const unsigned*)ei)[2 * t + 1];
    unsigned long long m = __ballot(hv != 0u);
    if (t == 0) s_is64 = (m == 0ull);
  }
  __syncthreads();
  int is64 = s_is64;
  size_t e0 = (size_t)blockIdx.x * BIN_CHUNK;
  int n = (int)(((e0 + BIN_CHUNK) <= N_EDGES) ? BIN_CHUNK : (N_EDGES - e0));
  // n is always a multiple of 4 (last block: 2048) => vector loads in-bounds

  unsigned rec[BIN_ITER];
  int pk[BIN_ITER];
#pragma unroll
  for (int i = 0; i < BIN_ITER; ++i) { rec[i] = 0xFFFFFFFFu; pk[i] = 0; }

  if (is64) {
    const long long* e = (const long long*)ei;
#pragma unroll
    for (int i = 0; i < BIN_ITER / 2; ++i) {       // 4 pair-iterations
      int k = 2 * t + 1024 * i;                    // even, 16B-aligned
      if (k < n) {
        uint4 sp = *(const uint4*)(e + e0 + k);                // src[k],src[k+1]
        uint4 dp = *(const uint4*)(e + (size_t)N_EDGES + e0 + k);
        make_rec(sp.x, dp.x, rec[2 * i],     pk[2 * i]);
        make_rec(sp.z, dp.z, rec[2 * i + 1], pk[2 * i + 1]);
      }
    }
  } else {
    const unsigned* e = (const unsigned*)ei;
#pragma unroll
    for (int i = 0; i < BIN_ITER / 4; ++i) {       // 2 quad-iterations
      int k = 4 * t + 2048 * i;                    // mult of 4, 16B-aligned
      if (k < n) {
        uint4 sq = *(const uint4*)(e + e0 + k);
        uint4 dq = *(const uint4*)(e + (size_t)N_EDGES + e0 + k);
        make_rec(sq.x, dq.x, rec[4 * i],     pk[4 * i]);
        make_rec(sq.y, dq.y, rec[4 * i + 1], pk[4 * i + 1]);
        make_rec(sq.z, dq.z, rec[4 * i + 2], pk[4 * i + 2]);
        make_rec(sq.w, dq.w, rec[4 * i + 3], pk[4 * i + 3]);
      }
    }
  }
  // rank-returning histogram; rank packed into pk bits 16..27
#pragma unroll
  for (int i = 0; i < BIN_ITER; ++i) {
    if (rec[i] != 0xFFFFFFFFu) {
      int r = atomicAdd(&lcnt[pk[i] & 0xFFFF], 1);
      pk[i] |= r << 16;
    }
  }
  __syncthreads();
  // scan 1024 bins (2 per thread) + global reservation
  int c0 = lcnt[2 * t], c1 = lcnt[2 * t + 1];
  int s = c0 + c1;
  int lane = t & 63, w = t >> 6;
  int incl = s;
#pragma unroll
  for (int o = 1; o < 64; o <<= 1) {
    int u = __shfl_up(incl, o);
    if (lane >= o) incl += u;
  }
  if (lane == 63) wsum[w] = incl;
  __syncthreads();
  int wb = 0;
  for (int i = 0; i < w; ++i) wb += wsum[i];
  int excl0 = wb + incl - s;
  int excl1 = excl0 + c0;
  lcnt[2 * t] = excl0; lcnt[2 * t + 1] = excl1;
  if (t == 128) s_th[0] = excl0;   // excl[256]
  if (t == 256) s_th[1] = excl0;   // excl[512]
  if (t == 384) s_th[2] = excl0;   // excl[768]
  if (t == 511) s_tot = excl1 + c1;
  // global reservation: result not needed until after placement -> latency hidden
  int gb0 = c0 ? atomicAdd(&gcur[2 * t], c0) : 0;
  int gb1 = c1 ? atomicAdd(&gcur[2 * t + 1], c1) : 0;
  __syncthreads();
  // place into staging (no atomics)
#pragma unroll
  for (int i = 0; i < BIN_ITER; ++i) {
    if (rec[i] != 0xFFFFFFFFu) {
      int p = lcnt[pk[i] & 0xFFFF] + (pk[i] >> 16);
      staging[p] = rec[i];
    }
  }
  __syncthreads();
  // overwrite lcnt with combo = gbase - excl
  lcnt[2 * t] = gb0 - excl0;
  lcnt[2 * t + 1] = gb1 - excl1;
  __syncthreads();
  // near-coalesced writeout; bucket recovered from staged low-8 + position
  int tot = s_tot, th0 = s_th[0], th1 = s_th[1], th2 = s_th[2];
  for (int j = t; j < tot; j += 512) {
    unsigned r = staging[j];
    int hi = (j >= th0) + (j >= th1) + (j >= th2);
    int b = (int)(r >> 24) | (hi << 8);
    int o = lcnt[b] + j;                 // == gbase[b] + (j - excl[b])
    if (o < CAP) perm1[(size_t)b * CAP + o] = r;
  }
}

// ---------------------------------------------------------------------------
// Per-bucket counting sort by dstLocal — zero per-record register state.
// Phase A: non-returning LDS histogram (records discarded).
// Phase B: scan -> 4-aligned segment offsets, offdeg, dinv.
// Phase C: re-read perm1 (block's own 40KB region, L2-hot: ~2.5MB/XCD),
//          returning atomicAdd on the cursor gives placement position.
// Phase D: coalesced uint4 writeout.
__global__ __launch_bounds__(512, 8) void k_sort(const int* __restrict__ gcur,
                                                 const unsigned* __restrict__ perm1,
                                                 unsigned* __restrict__ perm2,
                                                 int2* __restrict__ offdeg,
                                                 float* __restrict__ dinv) {
  __shared__ __align__(16) unsigned outbuf[OUT_CAP];   // 38.4 KB
  __shared__ int h[NPB];
  __shared__ int wsum2[2];
  __shared__ int s_tot;
  int b = blockIdx.x, t = threadIdx.x;
  if (t < NPB) h[t] = 0;
  __syncthreads();
  int cnt = min(gcur[b], SORT_CAP);
  int base = b * CAP;
  // phase A: histogram (no rank kept -> ds_add without return)
#pragma unroll
  for (int i = 0; i < SORT_V4; ++i) {
    int j = 4 * t + 2048 * i;          // max 10236+3 < CAP: load always in-bounds
    if (j < cnt) {
      uint4 q = *(const uint4*)(perm1 + base + j);
      atomicAdd(&h[(q.x >> 17) & (NPB - 1)], 1);
      if (j + 1 < cnt) atomicAdd(&h[(q.y >> 17) & (NPB - 1)], 1);
      if (j + 2 < cnt) atomicAdd(&h[(q.z >> 17) & (NPB - 1)], 1);
      if (j + 3 < cnt) atomicAdd(&h[(q.w >> 17) & (NPB - 1)], 1);
    }
  }
  __syncthreads();
  // phase B: scan 128 bins (threads 0..127), 4-aligned segments
  int degb = 0, degs4 = 0, incl = 0;
  if (t < NPB) {
    degb = h[t];
    degs4 = (degb + 3) & ~3;
    incl = degs4;
    int lane = t & 63;
#pragma unroll
    for (int o = 1; o < 64; o <<= 1) {
      int u = __shfl_up(incl, o);
      if (lane >= o) incl += u;
    }
    if (lane == 63) wsum2[t >> 6] = incl;
  }
  __syncthreads();
  int excl4 = 0;
  if (t < NPB) {
    excl4 = (t >= 64 ? wsum2[0] : 0) + incl - degs4;
    int node = b * NPB + t;
    if (node < N_NODES) {
      offdeg[node] = make_int2(base + excl4, degb);
      float dd = (float)degb + 1.0f;
      float y = rsqrtf(dd);
      y = y * (1.5f - 0.5f * dd * y * y);
      dinv[node] = y;
    }
    if (t == NPB - 1) s_tot = excl4 + degs4;
  }
  __syncthreads();
  if (t < NPB) h[t] = excl4;           // h becomes the placement cursor
  __syncthreads();
  // phase C: re-read + place (second atomic pass yields position directly)
#pragma unroll
  for (int i = 0; i < SORT_V4; ++i) {
    int j = 4 * t + 2048 * i;
    if (j < cnt) {
      uint4 q = *(const uint4*)(perm1 + base + j);
      { int p = atomicAdd(&h[(q.x >> 17) & (NPB - 1)], 1); outbuf[p] = q.x & 0x1FFFF; }
      if (j + 1 < cnt) { int p = atomicAdd(&h[(q.y >> 17) & (NPB - 1)], 1); outbuf[p] = q.y & 0x1FFFF; }
      if (j + 2 < cnt) { int p = atomicAdd(&h[(q.z >> 17) & (NPB - 1)], 1); outbuf[p] = q.z & 0x1FFFF; }
      if (j + 3 < cnt) { int p = atomicAdd(&h[(q.w >> 17) & (NPB - 1)], 1); outbuf[p] = q.w & 0x1FFFF; }
    }
  }
  __syncthreads();
  // phase D: coalesced writeout (tot and base are 4-aligned)
  int tot = s_tot;
#pragma unroll
  for (int i = 0; i < SORT_V4; ++i) {
    int j = 4 * t + 2048 * i;
    if (j < tot)
      *(uint4*)(perm2 + base + j) = *(const uint4*)(outbuf + j);
  }
}

// ---------------------------------------------------------------------------
// hs1 = dinv * (x @ W1).  One wave per node.
__global__ __launch_bounds__(256) void k_mm1(const float* __restrict__ x,
                                             const float* __restrict__ W1,
                                             const float* __restrict__ dinv,
                                             float* __restrict__ hs1) {
  int gid = blockIdx.x * blockDim.x + threadIdx.x;
  int node = gid >> 6;
  int lane = threadIdx.x & 63;
  if (node >= N_NODES) return;
  float2 v = ((const float2*)x)[(size_t)node * 64 + lane];
  float4 w0 = ((const float4*)W1)[2 * lane];
  float4 w1 = ((const float4*)W1)[2 * lane + 1];
  float a0 = v.x * w0.x + v.y * w1.x;
  float a1 = v.x * w0.y + v.y * w1.y;
  float a2 = v.x * w0.z + v.y * w1.z;
  float a3 = v.x * w0.w + v.y * w1.w;
#pragma unroll
  for (int off = 32; off > 0; off >>= 1) {
    a0 += __shfl_down(a0, off);
    a1 += __shfl_down(a1, off);
    a2 += __shfl_down(a2, off);
    a3 += __shfl_down(a3, off);
  }
  if (lane == 0) {
    float d = dinv[node];
    ((float4*)hs1)[node] = make_float4(d * a0, d * a1, d * a2, d * a3);
  }
}

// ---------------------------------------------------------------------------
// Atomic-free layer kernels: 16 lanes/node; uint4 record loads (coalesced),
// 4 independent gathers/lane; shfl tree reduce; fused epilogue.

__global__ __launch_bounds__(256) void k_l1(const int2* __restrict__ offdeg,
                                            const unsigned* __restrict__ perm2,
                                            const float* __restrict__ hs1,
                                            const float* __restrict__ dinv,
                                            const float* __restrict__ W2,
                                            const float* __restrict__ b1,
                                            float* __restrict__ hs2) {
  int node = blockIdx.x * 16 + (threadIdx.x >> 4);
  int l = threadIdx.x & 15;
  int2 od = offdeg[node];
  int base = od.x, d = od.y;
  float a0 = 0, a1 = 0, a2 = 0, a3 = 0;
  for (int j = 4 * l; j + 4 <= d; j += 64) {
    uint4 s = *(const uint4*)(perm2 + base + j);
    float4 v0 = ((const float4*)hs1)[s.x];
    float4 v1 = ((const float4*)hs1)[s.y];
    float4 v2 = ((const float4*)hs1)[s.z];
    float4 v3 = ((const float4*)hs1)[s.w];
    a0 += v0.x + v1.x + v2.x + v3.x;
    a1 += v0.y + v1.y + v2.y + v3.y;
    a2 += v0.z + v1.z + v2.z + v3.z;
    a3 += v0.w + v1.w + v2.w + v3.w;
  }
  int rb = d & ~3;
  if (l < d - rb) {
    float4 v = ((const float4*)hs1)[perm2[base + rb + l]];
    a0 += v.x; a1 += v.y; a2 += v.z; a3 += v.w;
  }
#pragma unroll
  for (int o = 8; o > 0; o >>= 1) {
    a0 += __shfl_down(a0, o); a1 += __shfl_down(a1, o);
    a2 += __shfl_down(a2, o); a3 += __shfl_down(a3, o);
  }
  if (l == 0) {
    float dn = dinv[node];
    float4 hl = ((const float4*)hs1)[node];
    float t0 = tanhf(dn * (a0 + hl.x) + b1[0]);
    float t1 = tanhf(dn * (a1 + hl.y) + b1[1]);
    float t2 = tanhf(dn * (a2 + hl.z) + b1[2]);
    float t3 = tanhf(dn * (a3 + hl.w) + b1[3]);
    float4 r;
    r.x = dn * (t0 * W2[0] + t1 * W2[4] + t2 * W2[8]  + t3 * W2[12]);
    r.y = dn * (t0 * W2[1] + t1 * W2[5] + t2 * W2[9]  + t3 * W2[13]);
    r.z = dn * (t0 * W2[2] + t1 * W2[6] + t2 * W2[10] + t3 * W2[14]);
    r.w = dn * (t0 * W2[3] + t1 * W2[7] + t2 * W2[11] + t3 * W2[15]);
    ((float4*)hs2)[node] = r;
  }
}

__global__ __launch_bounds__(256) void k_l2(const int2* __restrict__ offdeg,
                                            const unsigned* __restrict__ perm2,
                                            const float* __restrict__ hs2,
                                            const float* __restrict__ dinv,
                                            const float* __restrict__ W3,
                                            const float* __restrict__ b2,
                                            float* __restrict__ hs3) {
  int node = blockIdx.x * 16 + (threadIdx.x >> 4);
  int l = threadIdx.x & 15;
  int2 od = offdeg[node];
  int base = od.x, d = od.y;
  float a0 = 0, a1 = 0, a2 = 0, a3 = 0;
  for (int j = 4 * l; j + 4 <= d; j += 64) {
    uint4 s = *(const uint4*)(perm2 + base + j);
    float4 v0 = ((const float4*)hs2)[s.x];
    float4 v1 = ((const float4*)hs2)[s.y];
    float4 v2 = ((const float4*)hs2)[s.z];
    float4 v3 = ((const float4*)hs2)[s.w];
    a0 += v0.x + v1.x + v2.x + v3.x;
    a1 += v0.y + v1.y + v2.y + v3.y;
    a2 += v0.z + v1.z + v2.z + v3.z;
    a3 += v0.w + v1.w + v2.w + v3.w;
  }
  int rb = d & ~3;
  if (l < d - rb) {
    float4 v = ((const float4*)hs2)[perm2[base + rb + l]];
    a0 += v.x; a1 += v.y; a2 += v.z; a3 += v.w;
  }
#pragma unroll
  for (int o = 8; o > 0; o >>= 1) {
    a0 += __shfl_down(a0, o); a1 += __shfl_down(a1, o);
    a2 += __shfl_down(a2, o); a3 += __shfl_down(a3, o);
  }
  if (l == 0) {
    float dn = dinv[node];
    float4 hl = ((const float4*)hs2)[node];
    float t0 = tanhf(dn * (a0 + hl.x) + b2[0]);
    float t1 = tanhf(dn * (a1 + hl.y) + b2[1]);
    float t2 = tanhf(dn * (a2 + hl.z) + b2[2]);
    float t3 = tanhf(dn * (a3 + hl.w) + b2[3]);
    float2 r;
    r.x = dn * (t0 * W3[0] + t1 * W3[2] + t2 * W3[4] + t3 * W3[6]);
    r.y = dn * (t0 * W3[1] + t1 * W3[3] + t2 * W3[5] + t3 * W3[7]);
    ((float2*)hs3)[node] = r;
  }
}

__global__ __launch_bounds__(256) void k_l3(const int2* __restrict__ offdeg,
                                            const unsigned* __restrict__ perm2,
                                            const float* __restrict__ hs3,
                                            const float* __restrict__ dinv,
                                            const float* __restrict__ Wc,
                                            const float* __restrict__ bc,
                                            const float* __restrict__ b3,
                                            float* __restrict__ out) {
  int node = blockIdx.x * 16 + (threadIdx.x >> 4);
  int l = threadIdx.x & 15;
  int2 od = offdeg[node];
  int base = od.x, d = od.y;
  float a0 = 0, a1 = 0;
  for (int j = 4 * l; j + 4 <= d; j += 64) {
    uint4 s = *(const uint4*)(perm2 + base + j);
    float2 v0 = ((const float2*)hs3)[s.x];
    float2 v1 = ((const float2*)hs3)[s.y];
    float2 v2 = ((const float2*)hs3)[s.z];
    float2 v3 = ((const float2*)hs3)[s.w];
    a0 += v0.x + v1.x + v2.x + v3.x;
    a1 += v0.y + v1.y + v2.y + v3.y;
  }
  int rb = d & ~3;
  if (l < d - rb) {
    float2 v = ((const float2*)hs3)[perm2[base + rb + l]];
    a0 += v.x; a1 += v.y;
  }
  // butterfly: all 16 lanes end with the full sums (xor 8/4/2/1 stays in-group)
#pragma unroll
  for (int o = 8; o > 0; o >>= 1) {
    a0 += __shfl_xor(a0, o); a1 += __shfl_xor(a1, o);
  }
  float dn = dinv[node];
  float2 hl = ((const float2*)hs3)[node];
  float t0 = tanhf(dn * (a0 + hl.x) + b3[0]);
  float t1 = tanhf(dn * (a1 + hl.y) + b3[1]);
  // coalesced epilogue: 10 adjacent lanes write one class each (40B/node),
  // lanes 10/11 write the two h values
  if (l < 10)
    out[(size_t)node * 10 + l] = t0 * Wc[l] + t1 * Wc[10 + l] + bc[l];
  else if (l == 10)
    out[(size_t)N_NODES * 10 + 2 * node + 0] = t0;
  else if (l == 11)
    out[(size_t)N_NODES * 10 + 2 * node + 1] = t1;
}

// ---------------------------------------------------------------------------
extern "C" void kernel_launch(void* const* d_in, const int* in_sizes, int n_in,
                              void* d_out, int out_size, void* d_ws, size_t ws_size,
                              hipStream_t stream) {
  const float* x  = (const float*)d_in[0];
  const void*  ei = d_in[1];
  const float* W1 = (const float*)d_in[2];
  const float* b1 = (const float*)d_in[3];
  const float* W2 = (const float*)d_in[4];
  const float* b2 = (const float*)d_in[5];
  const float* W3 = (const float*)d_in[6];
  const float* b3 = (const float*)d_in[7];
  const float* Wc = (const float*)d_in[8];
  const float* bc = (const float*)d_in[9];
  float* out = (float*)d_out;

  const size_t N = N_NODES;
  float* base = (float*)d_ws;
  float* dinv = base;                            // N
  float* hs1  = base + N;                        // 4N
  float* hs2  = base + 5 * N;                    // 4N
  float* hs3  = base + 9 * N;                    // 2N
  int2*  offdeg = (int2*)(base + 11 * N);        // N int2 = 2N
  int*   gcur = (int*)(base + 13 * N);           // 1024
  unsigned* perm1 = (unsigned*)(base + 13 * N + 2048);   // NBKT*CAP (33.6 MB)
  unsigned* perm2 = perm1 + (size_t)NBKT * CAP;          // NBKT*CAP (33.6 MB)

  hipMemsetAsync(gcur, 0, 1024 * sizeof(int), stream);
  k_bin<<<NBIN_BLOCKS, BIN_THREADS, 0, stream>>>(ei, gcur, perm1);
  k_sort<<<NBKT, SORT_THREADS, 0, stream>>>(gcur, perm1, perm2, offdeg, dinv);
  k_mm1<<<(N_NODES * 64) / 256, 256, 0, stream>>>(x, W1, dinv, hs1);

  const int LB = N_NODES / 16;  // 6250
  k_l1<<<LB, 256, 0, stream>>>(offdeg, perm2, hs1, dinv, W2, b1, hs2);
  k_l2<<<LB, 256, 0, stream>>>(offdeg, perm2, hs2, dinv, W3, b2, hs3);
  k_l3<<<LB, 256, 0, stream>>>(offdeg, perm2, hs3, dinv, Wc, bc, b3, out);
}

// Round 4
// 286.902 us; speedup vs baseline: 1.1330x; 1.1330x over previous
//
#include <hip/hip_runtime.h>
#include <hip/hip_bf16.h>
#include <stdint.h>

#define N_NODES 100000
#define N_EDGES 6400000

#define NPB 128                                   // dst nodes per bucket
#define NBKT 782                                  // ceil(100000/128)
#define CAP 10752                                 // records/bucket stride
#define SORT_CAP 9216                             // per-bucket clamp (mean 8184, sigma~90, proven max ~8.5k)
#define OUT_CAP (SORT_CAP + NPB * 3)              // 9600: staging incl. 4-align padding
#define BIN_CHUNK 16384                           // long bucket runs (~21 recs) -> full-line writes
#define BIN_THREADS 512
#define SORT_THREADS 512
#define SORT_V4 5                                 // uint4 rounds: covers SORT_CAP
#define NBIN_BLOCKS ((N_EDGES + BIN_CHUNK - 1) / BIN_CHUNK)  // 391

// perm1 record: src (bits 0..16) | dstLocal (bits 17..23) | bktLow8 (bits 24..31)
//   src < 100000 < 0x1FFFF  =>  a valid record can never equal 0xFFFFFFFF
// perm2: src only, dst-sorted, segments 4-aligned (holes never read)

// ---------------------------------------------------------------------------
// Bin edges by dst bucket — zero per-record register state (records never
// held across barriers). Phase A: read edges + histogram (non-returning LDS
// atomic). Phase B: scan + global reservation. Phase C: RE-READ edges
// (~75% L3-resident per FETCH evidence), returning cursor atomic gives the
// staging slot. Phase D: near-coalesced writeout; 16K chunk makes bucket
// runs ~21 records (~84B) -> mostly full 64B lines (R3 showed k_bin time
// tracks scattered-write amplification).
// LDS ~74KB -> 2 blocks/CU (16 waves).
__global__ __launch_bounds__(512) void k_bin(const void* __restrict__ ei,
                                             int* __restrict__ gcur,
                                             unsigned* __restrict__ perm1) {
  __shared__ unsigned staging[BIN_CHUNK];          // 64 KB
  __shared__ int lcnt[1024];                       // counts -> placement cursor
  __shared__ int combo[1024];                      // gbase - excl
  __shared__ int wsum[8];
  __shared__ int s_tot;
  __shared__ int s_th[3];
  __shared__ int s_is64;
  int t = threadIdx.x;
  lcnt[t] = 0; lcnt[t + 512] = 0;
  if (t < 64) {
    unsigned hv = ((const unsigned*)ei)[2 * t + 1];
    unsigned long long m = __ballot(hv != 0u);
    if (t == 0) s_is64 = (m == 0ull);
  }
  __syncthreads();
  int is64 = s_is64;
  size_t e0 = (size_t)blockIdx.x * BIN_CHUNK;
  int n = (int)(((e0 + BIN_CHUNK) <= N_EDGES) ? BIN_CHUNK : (N_EDGES - e0));
  // n is a multiple of 4 (last block: 10240) => vector loads stay in-bounds

  // ---- phase A: histogram (records discarded) ----
  if (is64) {
    const long long* e = (const long long*)ei;
    for (int k = 2 * t; k < n; k += 1024) {        // 16 pair-iterations
      uint4 sp = *(const uint4*)(e + e0 + k);
      uint4 dp = *(const uint4*)(e + (size_t)N_EDGES + e0 + k);
      if (sp.x < N_NODES && dp.x < N_NODES) atomicAdd(&lcnt[dp.x >> 7], 1);
      if (sp.z < N_NODES && dp.z < N_NODES) atomicAdd(&lcnt[dp.z >> 7], 1);
    }
  } else {
    const unsigned* e = (const unsigned*)ei;
    for (int k = 4 * t; k < n; k += 2048) {        // 8 quad-iterations
      uint4 sq = *(const uint4*)(e + e0 + k);
      uint4 dq = *(const uint4*)(e + (size_t)N_EDGES + e0 + k);
      if (sq.x < N_NODES && dq.x < N_NODES) atomicAdd(&lcnt[dq.x >> 7], 1);
      if (sq.y < N_NODES && dq.y < N_NODES) atomicAdd(&lcnt[dq.y >> 7], 1);
      if (sq.z < N_NODES && dq.z < N_NODES) atomicAdd(&lcnt[dq.z >> 7], 1);
      if (sq.w < N_NODES && dq.w < N_NODES) atomicAdd(&lcnt[dq.w >> 7], 1);
    }
  }
  __syncthreads();
  // ---- phase B: scan 1024 bins (2 per thread) + global reservation ----
  int c0 = lcnt[2 * t], c1 = lcnt[2 * t + 1];
  int s = c0 + c1;
  int lane = t & 63, w = t >> 6;
  int incl = s;
#pragma unroll
  for (int o = 1; o < 64; o <<= 1) {
    int u = __shfl_up(incl, o);
    if (lane >= o) incl += u;
  }
  if (lane == 63) wsum[w] = incl;
  __syncthreads();
  int wb = 0;
  for (int i = 0; i < w; ++i) wb += wsum[i];
  int excl0 = wb + incl - s;
  int excl1 = excl0 + c0;
  int gb0 = c0 ? atomicAdd(&gcur[2 * t], c0) : 0;
  int gb1 = c1 ? atomicAdd(&gcur[2 * t + 1], c1) : 0;
  lcnt[2 * t] = excl0; lcnt[2 * t + 1] = excl1;   // placement cursors
  combo[2 * t] = gb0 - excl0;
  combo[2 * t + 1] = gb1 - excl1;
  if (t == 128) s_th[0] = excl0;   // excl[256]
  if (t == 256) s_th[1] = excl0;   // excl[512]
  if (t == 384) s_th[2] = excl0;   // excl[768]
  if (t == 511) s_tot = excl1 + c1;
  __syncthreads();
  // ---- phase C: re-read edges, place via returning cursor atomic ----
  if (is64) {
    const long long* e = (const long long*)ei;
    for (int k = 2 * t; k < n; k += 1024) {
      uint4 sp = *(const uint4*)(e + e0 + k);
      uint4 dp = *(const uint4*)(e + (size_t)N_EDGES + e0 + k);
      if (sp.x < N_NODES && dp.x < N_NODES) {
        int p = atomicAdd(&lcnt[dp.x >> 7], 1);
        staging[p] = sp.x | ((dp.x & (NPB - 1u)) << 17) | (((dp.x >> 7) & 255u) << 24);
      }
      if (sp.z < N_NODES && dp.z < N_NODES) {
        int p = atomicAdd(&lcnt[dp.z >> 7], 1);
        staging[p] = sp.z | ((dp.z & (NPB - 1u)) << 17) | (((dp.z >> 7) & 255u) << 24);
      }
    }
  } else {
    const unsigned* e = (const unsigned*)ei;
    for (int k = 4 * t; k < n; k += 2048) {
      uint4 sq = *(const uint4*)(e + e0 + k);
      uint4 dq = *(const uint4*)(e + (size_t)N_EDGES + e0 + k);
      if (sq.x < N_NODES && dq.x < N_NODES) {
        int p = atomicAdd(&lcnt[dq.x >> 7], 1);
        staging[p] = sq.x | ((dq.x & (NPB - 1u)) << 17) | (((dq.x >> 7) & 255u) << 24);
      }
      if (sq.y < N_NODES && dq.y < N_NODES) {
        int p = atomicAdd(&lcnt[dq.y >> 7], 1);
        staging[p] = sq.y | ((dq.y & (NPB - 1u)) << 17) | (((dq.y >> 7) & 255u) << 24);
      }
      if (sq.z < N_NODES && dq.z < N_NODES) {
        int p = atomicAdd(&lcnt[dq.z >> 7], 1);
        staging[p] = sq.z | ((dq.z & (NPB - 1u)) << 17) | (((dq.z >> 7) & 255u) << 24);
      }
      if (sq.w < N_NODES && dq.w < N_NODES) {
        int p = atomicAdd(&lcnt[dq.w >> 7], 1);
        staging[p] = sq.w | ((dq.w & (NPB - 1u)) << 17) | (((dq.w >> 7) & 255u) << 24);
      }
    }
  }
  __syncthreads();
  // ---- phase D: writeout; bucket recovered from staged low-8 + position ----
  int tot = s_tot, th0 = s_th[0], th1 = s_th[1], th2 = s_th[2];
  for (int j = t; j < tot; j += 512) {
    unsigned r = staging[j];
    int hi = (j >= th0) + (j >= th1) + (j >= th2);
    int b = (int)(r >> 24) | (hi << 8);
    int o = combo[b] + j;                // == gbase[b] + (j - excl[b])
    if (o < CAP) perm1[(size_t)b * CAP + o] = r;
  }
}

// ---------------------------------------------------------------------------
// Per-bucket counting sort by dstLocal (R2-proven version). uint4 record
// loads (4/instr), rank-returning LDS atomics; uint4 writeout (tot and base
// are 4-aligned). outbuf 38.4KB -> 4 blocks/CU.
__global__ __launch_bounds__(512) void k_sort(const int* __restrict__ gcur,
                                              const unsigned* __restrict__ perm1,
                                              unsigned* __restrict__ perm2,
                                              int2* __restrict__ offdeg,
                                              float* __restrict__ dinv) {
  __shared__ __align__(16) unsigned outbuf[OUT_CAP];
  __shared__ int h[NPB];
  __shared__ int wsum2[2];
  __shared__ int s_tot;
  int b = blockIdx.x, t = threadIdx.x;
  if (t < NPB) h[t] = 0;
  __syncthreads();
  int cnt = min(gcur[b], SORT_CAP);
  int base = b * CAP;
  unsigned rec[4 * SORT_V4];
  short rnk[4 * SORT_V4];
#pragma unroll
  for (int i = 0; i < SORT_V4; ++i) {
    int j = 4 * t + 2048 * i;          // max 10236+3 < CAP: load always in-bounds
    uint4 q = *(const uint4*)(perm1 + base + j);
    rec[4 * i]     = (j     < cnt) ? q.x : 0xFFFFFFFFu;
    rec[4 * i + 1] = (j + 1 < cnt) ? q.y : 0xFFFFFFFFu;
    rec[4 * i + 2] = (j + 2 < cnt) ? q.z : 0xFFFFFFFFu;
    rec[4 * i + 3] = (j + 3 < cnt) ? q.w : 0xFFFFFFFFu;
  }
#pragma unroll
  for (int i = 0; i < 4 * SORT_V4; ++i) {
    rnk[i] = 0;
    if (rec[i] != 0xFFFFFFFFu)
      rnk[i] = (short)atomicAdd(&h[(rec[i] >> 17) & (NPB - 1)], 1);
  }
  __syncthreads();
  // scan 128 bins (threads 0..127), 4-aligned segments
  int degb = 0, degs4 = 0, incl = 0;
  if (t < NPB) {
    degb = h[t];
    degs4 = (degb + 3) & ~3;
    incl = degs4;
    int lane = t & 63;
#pragma unroll
    for (int o = 1; o < 64; o <<= 1) {
      int u = __shfl_up(incl, o);
      if (lane >= o) incl += u;
    }
    if (lane == 63) wsum2[t >> 6] = incl;
  }
  __syncthreads();
  int excl4 = 0;
  if (t < NPB) {
    excl4 = (t >= 64 ? wsum2[0] : 0) + incl - degs4;
    int node = b * NPB + t;
    if (node < N_NODES) {
      offdeg[node] = make_int2(base + excl4, degb);
      float dd = (float)degb + 1.0f;
      float y = rsqrtf(dd);
      y = y * (1.5f - 0.5f * dd * y * y);
      dinv[node] = y;
    }
    if (t == NPB - 1) s_tot = excl4 + degs4;
  }
  __syncthreads();
  if (t < NPB) h[t] = excl4;
  __syncthreads();
  // place (no atomics); mask strips dstLocal + packed bucket bits
#pragma unroll
  for (int i = 0; i < 4 * SORT_V4; ++i) {
    if (rec[i] != 0xFFFFFFFFu)
      outbuf[h[(rec[i] >> 17) & (NPB - 1)] + rnk[i]] = rec[i] & 0x1FFFF;
  }
  __syncthreads();
  int tot = s_tot;                     // 4-aligned; base 4-aligned
#pragma unroll
  for (int i = 0; i < SORT_V4; ++i) {
    int j = 4 * t + 2048 * i;
    if (j < tot)
      *(uint4*)(perm2 + base + j) = *(const uint4*)(outbuf + j);
  }
}

// ---------------------------------------------------------------------------
// hs1 = dinv * (x @ W1).  One wave per node.
__global__ __launch_bounds__(256) void k_mm1(const float* __restrict__ x,
                                             const float* __restrict__ W1,
                                             const float* __restrict__ dinv,
                                             float* __restrict__ hs1) {
  int gid = blockIdx.x * blockDim.x + threadIdx.x;
  int node = gid >> 6;
  int lane = threadIdx.x & 63;
  if (node >= N_NODES) return;
  float2 v = ((const float2*)x)[(size_t)node * 64 + lane];
  float4 w0 = ((const float4*)W1)[2 * lane];
  float4 w1 = ((const float4*)W1)[2 * lane + 1];
  float a0 = v.x * w0.x + v.y * w1.x;
  float a1 = v.x * w0.y + v.y * w1.y;
  float a2 = v.x * w0.z + v.y * w1.z;
  float a3 = v.x * w0.w + v.y * w1.w;
#pragma unroll
  for (int off = 32; off > 0; off >>= 1) {
    a0 += __shfl_down(a0, off);
    a1 += __shfl_down(a1, off);
    a2 += __shfl_down(a2, off);
    a3 += __shfl_down(a3, off);
  }
  if (lane == 0) {
    float d = dinv[node];
    ((float4*)hs1)[node] = make_float4(d * a0, d * a1, d * a2, d * a3);
  }
}

// ---------------------------------------------------------------------------
// Atomic-free layer kernels: 16 lanes/node; uint4 record loads (coalesced),
// 4 independent gathers/lane; shfl tree reduce; fused epilogue.

__global__ __launch_bounds__(256) void k_l1(const int2* __restrict__ offdeg,
                                            const unsigned* __restrict__ perm2,
                                            const float* __restrict__ hs1,
                                            const float* __restrict__ dinv,
                                            const float* __restrict__ W2,
                                            const float* __restrict__ b1,
                                            float* __restrict__ hs2) {
  int node = blockIdx.x * 16 + (threadIdx.x >> 4);
  int l = threadIdx.x & 15;
  int2 od = offdeg[node];
  int base = od.x, d = od.y;
  float a0 = 0, a1 = 0, a2 = 0, a3 = 0;
  for (int j = 4 * l; j + 4 <= d; j += 64) {
    uint4 s = *(const uint4*)(perm2 + base + j);
    float4 v0 = ((const float4*)hs1)[s.x];
    float4 v1 = ((const float4*)hs1)[s.y];
    float4 v2 = ((const float4*)hs1)[s.z];
    float4 v3 = ((const float4*)hs1)[s.w];
    a0 += v0.x + v1.x + v2.x + v3.x;
    a1 += v0.y + v1.y + v2.y + v3.y;
    a2 += v0.z + v1.z + v2.z + v3.z;
    a3 += v0.w + v1.w + v2.w + v3.w;
  }
  int rb = d & ~3;
  if (l < d - rb) {
    float4 v = ((const float4*)hs1)[perm2[base + rb + l]];
    a0 += v.x; a1 += v.y; a2 += v.z; a3 += v.w;
  }
#pragma unroll
  for (int o = 8; o > 0; o >>= 1) {
    a0 += __shfl_down(a0, o); a1 += __shfl_down(a1, o);
    a2 += __shfl_down(a2, o); a3 += __shfl_down(a3, o);
  }
  if (l == 0) {
    float dn = dinv[node];
    float4 hl = ((const float4*)hs1)[node];
    float t0 = tanhf(dn * (a0 + hl.x) + b1[0]);
    float t1 = tanhf(dn * (a1 + hl.y) + b1[1]);
    float t2 = tanhf(dn * (a2 + hl.z) + b1[2]);
    float t3 = tanhf(dn * (a3 + hl.w) + b1[3]);
    float4 r;
    r.x = dn * (t0 * W2[0] + t1 * W2[4] + t2 * W2[8]  + t3 * W2[12]);
    r.y = dn * (t0 * W2[1] + t1 * W2[5] + t2 * W2[9]  + t3 * W2[13]);
    r.z = dn * (t0 * W2[2] + t1 * W2[6] + t2 * W2[10] + t3 * W2[14]);
    r.w = dn * (t0 * W2[3] + t1 * W2[7] + t2 * W2[11] + t3 * W2[15]);
    ((float4*)hs2)[node] = r;
  }
}

__global__ __launch_bounds__(256) void k_l2(const int2* __restrict__ offdeg,
                                            const unsigned* __restrict__ perm2,
                                            const float* __restrict__ hs2,
                                            const float* __restrict__ dinv,
                                            const float* __restrict__ W3,
                                            const float* __restrict__ b2,
                                            float* __restrict__ hs3) {
  int node = blockIdx.x * 16 + (threadIdx.x >> 4);
  int l = threadIdx.x & 15;
  int2 od = offdeg[node];
  int base = od.x, d = od.y;
  float a0 = 0, a1 = 0, a2 = 0, a3 = 0;
  for (int j = 4 * l; j + 4 <= d; j += 64) {
    uint4 s = *(const uint4*)(perm2 + base + j);
    float4 v0 = ((const float4*)hs2)[s.x];
    float4 v1 = ((const float4*)hs2)[s.y];
    float4 v2 = ((const float4*)hs2)[s.z];
    float4 v3 = ((const float4*)hs2)[s.w];
    a0 += v0.x + v1.x + v2.x + v3.x;
    a1 += v0.y + v1.y + v2.y + v3.y;
    a2 += v0.z + v1.z + v2.z + v3.z;
    a3 += v0.w + v1.w + v2.w + v3.w;
  }
  int rb = d & ~3;
  if (l < d - rb) {
    float4 v = ((const float4*)hs2)[perm2[base + rb + l]];
    a0 += v.x; a1 += v.y; a2 += v.z; a3 += v.w;
  }
#pragma unroll
  for (int o = 8; o > 0; o >>= 1) {
    a0 += __shfl_down(a0, o); a1 += __shfl_down(a1, o);
    a2 += __shfl_down(a2, o); a3 += __shfl_down(a3, o);
  }
  if (l == 0) {
    float dn = dinv[node];
    float4 hl = ((const float4*)hs2)[node];
    float t0 = tanhf(dn * (a0 + hl.x) + b2[0]);
    float t1 = tanhf(dn * (a1 + hl.y) + b2[1]);
    float t2 = tanhf(dn * (a2 + hl.z) + b2[2]);
    float t3 = tanhf(dn * (a3 + hl.w) + b2[3]);
    float2 r;
    r.x = dn * (t0 * W3[0] + t1 * W3[2] + t2 * W3[4] + t3 * W3[6]);
    r.y = dn * (t0 * W3[1] + t1 * W3[3] + t2 * W3[5] + t3 * W3[7]);
    ((float2*)hs3)[node] = r;
  }
}

__global__ __launch_bounds__(256) void k_l3(const int2* __restrict__ offdeg,
                                            const unsigned* __restrict__ perm2,
                                            const float* __restrict__ hs3,
                                            const float* __restrict__ dinv,
                                            const float* __restrict__ Wc,
                                            const float* __restrict__ bc,
                                            const float* __restrict__ b3,
                                            float* __restrict__ out) {
  int node = blockIdx.x * 16 + (threadIdx.x >> 4);
  int l = threadIdx.x & 15;
  int2 od = offdeg[node];
  int base = od.x, d = od.y;
  float a0 = 0, a1 = 0;
  for (int j = 4 * l; j + 4 <= d; j += 64) {
    uint4 s = *(const uint4*)(perm2 + base + j);
    float2 v0 = ((const float2*)hs3)[s.x];
    float2 v1 = ((const float2*)hs3)[s.y];
    float2 v2 = ((const float2*)hs3)[s.z];
    float2 v3 = ((const float2*)hs3)[s.w];
    a0 += v0.x + v1.x + v2.x + v3.x;
    a1 += v0.y + v1.y + v2.y + v3.y;
  }
  int rb = d & ~3;
  if (l < d - rb) {
    float2 v = ((const float2*)hs3)[perm2[base + rb + l]];
    a0 += v.x; a1 += v.y;
  }
  // butterfly: all 16 lanes end with the full sums (xor 8/4/2/1 stays in-group)
#pragma unroll
  for (int o = 8; o > 0; o >>= 1) {
    a0 += __shfl_xor(a0, o); a1 += __shfl_xor(a1, o);
  }
  float dn = dinv[node];
  float2 hl = ((const float2*)hs3)[node];
  float t0 = tanhf(dn * (a0 + hl.x) + b3[0]);
  float t1 = tanhf(dn * (a1 + hl.y) + b3[1]);
  // coalesced epilogue: 10 adjacent lanes write one class each (40B/node),
  // lanes 10/11 write the two h values
  if (l < 10)
    out[(size_t)node * 10 + l] = t0 * Wc[l] + t1 * Wc[10 + l] + bc[l];
  else if (l == 10)
    out[(size_t)N_NODES * 10 + 2 * node + 0] = t0;
  else if (l == 11)
    out[(size_t)N_NODES * 10 + 2 * node + 1] = t1;
}

// ---------------------------------------------------------------------------
extern "C" void kernel_launch(void* const* d_in, const int* in_sizes, int n_in,
                              void* d_out, int out_size, void* d_ws, size_t ws_size,
                              hipStream_t stream) {
  const float* x  = (const float*)d_in[0];
  const void*  ei = d_in[1];
  const float* W1 = (const float*)d_in[2];
  const float* b1 = (const float*)d_in[3];
  const float* W2 = (const float*)d_in[4];
  const float* b2 = (const float*)d_in[5];
  const float* W3 = (const float*)d_in[6];
  const float* b3 = (const float*)d_in[7];
  const float* Wc = (const float*)d_in[8];
  const float* bc = (const float*)d_in[9];
  float* out = (float*)d_out;

  const size_t N = N_NODES;
  float* base = (float*)d_ws;
  float* dinv = base;                            // N
  float* hs1  = base + N;                        // 4N
  float* hs2  = base + 5 * N;                    // 4N
  float* hs3  = base + 9 * N;                    // 2N
  int2*  offdeg = (int2*)(base + 11 * N);        // N int2 = 2N
  int*   gcur = (int*)(base + 13 * N);           // 1024
  unsigned* perm1 = (unsigned*)(base + 13 * N + 2048);   // NBKT*CAP (33.6 MB)
  unsigned* perm2 = perm1 + (size_t)NBKT * CAP;          // NBKT*CAP (33.6 MB)

  hipMemsetAsync(gcur, 0, 1024 * sizeof(int), stream);
  k_bin<<<NBIN_BLOCKS, BIN_THREADS, 0, stream>>>(ei, gcur, perm1);
  k_sort<<<NBKT, SORT_THREADS, 0, stream>>>(gcur, perm1, perm2, offdeg, dinv);
  k_mm1<<<(N_NODES * 64) / 256, 256, 0, stream>>>(x, W1, dinv, hs1);

  const int LB = N_NODES / 16;  // 6250
  k_l1<<<LB, 256, 0, stream>>>(offdeg, perm2, hs1, dinv, W2, b1, hs2);
  k_l2<<<LB, 256, 0, stream>>>(offdeg, perm2, hs2, dinv, W3, b2, hs3);
  k_l3<<<LB, 256, 0, stream>>>(offdeg, perm2, hs3, dinv, Wc, bc, b3, out);
}

// Round 6
// 278.972 us; speedup vs baseline: 1.1652x; 1.0284x over previous
//
#include <hip/hip_runtime.h>
#include <hip/hip_bf16.h>
#include <stdint.h>

#define N_NODES 100000
#define N_EDGES 6400000

#define NPB 128                                   // dst nodes per bucket
#define NBKT 782                                  // ceil(100000/128)
#define CAP 10752                                 // records/bucket stride
#define SORT_CAP 9216                             // per-bucket clamp (mean 8184, sigma~90, proven max ~8.5k)
#define OUT_CAP (SORT_CAP + NPB * 3)              // 9600: staging incl. 4-align padding
#define BIN_CHUNK 16384                           // long bucket runs (~21 recs) -> full-line writes
#define BIN_THREADS 1024                          // 16 waves/block x 2 blocks/CU = 32 waves (100%)
#define SORT_THREADS 512
#define SORT_V4 5                                 // uint4 rounds: covers SORT_CAP
#define NBIN_BLOCKS ((N_EDGES + BIN_CHUNK - 1) / BIN_CHUNK)  // 391

// perm1 record: src (bits 0..16) | dstLocal (bits 17..23) | bktLow8 (bits 24..31)
//   src < 100000 < 0x1FFFF  =>  a valid record can never equal 0xFFFFFFFF
// perm2: src only, dst-sorted, segments 4-aligned (holes never read)

// ---------------------------------------------------------------------------
// Bin edges by dst bucket — zero per-record register state. Phase A: read
// edges + histogram (non-returning LDS atomic). Phase B: 1-bin-per-thread
// scan + global reservation. Phase C: re-read edges (L3-absorbed), returning
// cursor atomic gives staging slot. Phase D: near-coalesced writeout.
// 1024 threads: same 72.5KB LDS (2 blocks/CU) but 32 waves/CU -> full
// occupancy (R4 was 16 waves, latency-limited at 26% occupancy).
__global__ __launch_bounds__(1024) void k_bin(const void* __restrict__ ei,
                                              int* __restrict__ gcur,
                                              unsigned* __restrict__ perm1) {
  __shared__ unsigned staging[BIN_CHUNK];          // 64 KB
  __shared__ int lcnt[1024];                       // counts -> placement cursor
  __shared__ int combo[1024];                      // gbase - excl
  __shared__ int wsum[16];
  __shared__ int s_tot;
  __shared__ int s_th[3];
  __shared__ int s_is64;
  int t = threadIdx.x;
  lcnt[t] = 0;
  if (t < 64) {
    unsigned hv = ((const unsigned*)ei)[2 * t + 1];
    unsigned long long m = __ballot(hv != 0u);
    if (t == 0) s_is64 = (m == 0ull);
  }
  __syncthreads();
  int is64 = s_is64;
  size_t e0 = (size_t)blockIdx.x * BIN_CHUNK;
  int n = (int)(((e0 + BIN_CHUNK) <= N_EDGES) ? BIN_CHUNK : (N_EDGES - e0));
  // n is a multiple of 2048 (last block: 10240) => vector loops stay in-bounds

  // ---- phase A: histogram (records discarded) ----
  if (is64) {
    const long long* e = (const long long*)ei;
    for (int k = 2 * t; k < n; k += 2048) {        // 8 pair-iterations
      uint4 sp = *(const uint4*)(e + e0 + k);
      uint4 dp = *(const uint4*)(e + (size_t)N_EDGES + e0 + k);
      if (sp.x < N_NODES && dp.x < N_NODES) atomicAdd(&lcnt[dp.x >> 7], 1);
      if (sp.z < N_NODES && dp.z < N_NODES) atomicAdd(&lcnt[dp.z >> 7], 1);
    }
  } else {
    const unsigned* e = (const unsigned*)ei;
    for (int k = 4 * t; k < n; k += 4096) {        // 4 quad-iterations
      uint4 sq = *(const uint4*)(e + e0 + k);
      uint4 dq = *(const uint4*)(e + (size_t)N_EDGES + e0 + k);
      if (sq.x < N_NODES && dq.x < N_NODES) atomicAdd(&lcnt[dq.x >> 7], 1);
      if (sq.y < N_NODES && dq.y < N_NODES) atomicAdd(&lcnt[dq.y >> 7], 1);
      if (sq.z < N_NODES && dq.z < N_NODES) atomicAdd(&lcnt[dq.z >> 7], 1);
      if (sq.w < N_NODES && dq.w < N_NODES) atomicAdd(&lcnt[dq.w >> 7], 1);
    }
  }
  __syncthreads();
  // ---- phase B: scan 1024 bins (1 per thread) + global reservation ----
  int c = lcnt[t];
  int lane = t & 63, w = t >> 6;
  int incl = c;
#pragma unroll
  for (int o = 1; o < 64; o <<= 1) {
    int u = __shfl_up(incl, o);
    if (lane >= o) incl += u;
  }
  if (lane == 63) wsum[w] = incl;
  __syncthreads();
  int wb = 0;
  for (int i = 0; i < w; ++i) wb += wsum[i];
  int excl = wb + incl - c;
  int gb = c ? atomicAdd(&gcur[t], c) : 0;
  lcnt[t] = excl;                       // placement cursor
  combo[t] = gb - excl;
  if (t == 256) s_th[0] = excl;         // excl[256]
  if (t == 512) s_th[1] = excl;         // excl[512]
  if (t == 768) s_th[2] = excl;         // excl[768]
  if (t == 1023) s_tot = excl + c;
  __syncthreads();
  // ---- phase C: re-read edges, place via returning cursor atomic ----
  if (is64) {
    const long long* e = (const long long*)ei;
    for (int k = 2 * t; k < n; k += 2048) {
      uint4 sp = *(const uint4*)(e + e0 + k);
      uint4 dp = *(const uint4*)(e + (size_t)N_EDGES + e0 + k);
      if (sp.x < N_NODES && dp.x < N_NODES) {
        int p = atomicAdd(&lcnt[dp.x >> 7], 1);
        staging[p] = sp.x | ((dp.x & (NPB - 1u)) << 17) | (((dp.x >> 7) & 255u) << 24);
      }
      if (sp.z < N_NODES && dp.z < N_NODES) {
        int p = atomicAdd(&lcnt[dp.z >> 7], 1);
        staging[p] = sp.z | ((dp.z & (NPB - 1u)) << 17) | (((dp.z >> 7) & 255u) << 24);
      }
    }
  } else {
    const unsigned* e = (const unsigned*)ei;
    for (int k = 4 * t; k < n; k += 4096) {
      uint4 sq = *(const uint4*)(e + e0 + k);
      uint4 dq = *(const uint4*)(e + (size_t)N_EDGES + e0 + k);
      if (sq.x < N_NODES && dq.x < N_NODES) {
        int p = atomicAdd(&lcnt[dq.x >> 7], 1);
        staging[p] = sq.x | ((dq.x & (NPB - 1u)) << 17) | (((dq.x >> 7) & 255u) << 24);
      }
      if (sq.y < N_NODES && dq.y < N_NODES) {
        int p = atomicAdd(&lcnt[dq.y >> 7], 1);
        staging[p] = sq.y | ((dq.y & (NPB - 1u)) << 17) | (((dq.y >> 7) & 255u) << 24);
      }
      if (sq.z < N_NODES && dq.z < N_NODES) {
        int p = atomicAdd(&lcnt[dq.z >> 7], 1);
        staging[p] = sq.z | ((dq.z & (NPB - 1u)) << 17) | (((dq.z >> 7) & 255u) << 24);
      }
      if (sq.w < N_NODES && dq.w < N_NODES) {
        int p = atomicAdd(&lcnt[dq.w >> 7], 1);
        staging[p] = sq.w | ((dq.w & (NPB - 1u)) << 17) | (((dq.w >> 7) & 255u) << 24);
      }
    }
  }
  __syncthreads();
  // ---- phase D: writeout; bucket recovered from staged low-8 + position ----
  int tot = s_tot, th0 = s_th[0], th1 = s_th[1], th2 = s_th[2];
  for (int j = t; j < tot; j += 1024) {
    unsigned r = staging[j];
    int hi = (j >= th0) + (j >= th1) + (j >= th2);
    int b = (int)(r >> 24) | (hi << 8);
    int o = combo[b] + j;                // == gbase[b] + (j - excl[b])
    if (o < CAP) perm1[(size_t)b * CAP + o] = r;
  }
}

// ---------------------------------------------------------------------------
// Per-bucket counting sort by dstLocal (R2-proven version). uint4 record
// loads (4/instr), rank-returning LDS atomics; uint4 writeout (tot and base
// are 4-aligned). outbuf 38.4KB -> 4 blocks/CU.
__global__ __launch_bounds__(512) void k_sort(const int* __restrict__ gcur,
                                              const unsigned* __restrict__ perm1,
                                              unsigned* __restrict__ perm2,
                                              int2* __restrict__ offdeg,
                                              float* __restrict__ dinv) {
  __shared__ __align__(16) unsigned outbuf[OUT_CAP];
  __shared__ int h[NPB];
  __shared__ int wsum2[2];
  __shared__ int s_tot;
  int b = blockIdx.x, t = threadIdx.x;
  if (t < NPB) h[t] = 0;
  __syncthreads();
  int cnt = min(gcur[b], SORT_CAP);
  int base = b * CAP;
  unsigned rec[4 * SORT_V4];
  short rnk[4 * SORT_V4];
#pragma unroll
  for (int i = 0; i < SORT_V4; ++i) {
    int j = 4 * t + 2048 * i;          // max 10236+3 < CAP: load always in-bounds
    uint4 q = *(const uint4*)(perm1 + base + j);
    rec[4 * i]     = (j     < cnt) ? q.x : 0xFFFFFFFFu;
    rec[4 * i + 1] = (j + 1 < cnt) ? q.y : 0xFFFFFFFFu;
    rec[4 * i + 2] = (j + 2 < cnt) ? q.z : 0xFFFFFFFFu;
    rec[4 * i + 3] = (j + 3 < cnt) ? q.w : 0xFFFFFFFFu;
  }
#pragma unroll
  for (int i = 0; i < 4 * SORT_V4; ++i) {
    rnk[i] = 0;
    if (rec[i] != 0xFFFFFFFFu)
      rnk[i] = (short)atomicAdd(&h[(rec[i] >> 17) & (NPB - 1)], 1);
  }
  __syncthreads();
  // scan 128 bins (threads 0..127), 4-aligned segments
  int degb = 0, degs4 = 0, incl = 0;
  if (t < NPB) {
    degb = h[t];
    degs4 = (degb + 3) & ~3;
    incl = degs4;
    int lane = t & 63;
#pragma unroll
    for (int o = 1; o < 64; o <<= 1) {
      int u = __shfl_up(incl, o);
      if (lane >= o) incl += u;
    }
    if (lane == 63) wsum2[t >> 6] = incl;
  }
  __syncthreads();
  int excl4 = 0;
  if (t < NPB) {
    excl4 = (t >= 64 ? wsum2[0] : 0) + incl - degs4;
    int node = b * NPB + t;
    if (node < N_NODES) {
      offdeg[node] = make_int2(base + excl4, degb);
      float dd = (float)degb + 1.0f;
      float y = rsqrtf(dd);
      y = y * (1.5f - 0.5f * dd * y * y);
      dinv[node] = y;
    }
    if (t == NPB - 1) s_tot = excl4 + degs4;
  }
  __syncthreads();
  if (t < NPB) h[t] = excl4;
  __syncthreads();
  // place (no atomics); mask strips dstLocal + packed bucket bits
#pragma unroll
  for (int i = 0; i < 4 * SORT_V4; ++i) {
    if (rec[i] != 0xFFFFFFFFu)
      outbuf[h[(rec[i] >> 17) & (NPB - 1)] + rnk[i]] = rec[i] & 0x1FFFF;
  }
  __syncthreads();
  int tot = s_tot;                     // 4-aligned; base 4-aligned
#pragma unroll
  for (int i = 0; i < SORT_V4; ++i) {
    int j = 4 * t + 2048 * i;
    if (j < tot)
      *(uint4*)(perm2 + base + j) = *(const uint4*)(outbuf + j);
  }
}

// ---------------------------------------------------------------------------
// hs1 = dinv * (x @ W1).  One wave per node.
__global__ __launch_bounds__(256) void k_mm1(const float* __restrict__ x,
                                             const float* __restrict__ W1,
                                             const float* __restrict__ dinv,
                                             float* __restrict__ hs1) {
  int gid = blockIdx.x * blockDim.x + threadIdx.x;
  int node = gid >> 6;
  int lane = threadIdx.x & 63;
  if (node >= N_NODES) return;
  float2 v = ((const float2*)x)[(size_t)node * 64 + lane];
  float4 w0 = ((const float4*)W1)[2 * lane];
  float4 w1 = ((const float4*)W1)[2 * lane + 1];
  float a0 = v.x * w0.x + v.y * w1.x;
  float a1 = v.x * w0.y + v.y * w1.y;
  float a2 = v.x * w0.z + v.y * w1.z;
  float a3 = v.x * w0.w + v.y * w1.w;
#pragma unroll
  for (int off = 32; off > 0; off >>= 1) {
    a0 += __shfl_down(a0, off);
    a1 += __shfl_down(a1, off);
    a2 += __shfl_down(a2, off);
    a3 += __shfl_down(a3, off);
  }
  if (lane == 0) {
    float d = dinv[node];
    ((float4*)hs1)[node] = make_float4(d * a0, d * a1, d * a2, d * a3);
  }
}

// ---------------------------------------------------------------------------
// Atomic-free layer kernels: 16 lanes/node; uint4 record loads (coalesced),
// 4 independent gathers/lane; shfl tree reduce; fused epilogue.

__global__ __launch_bounds__(256) void k_l1(const int2* __restrict__ offdeg,
                                            const unsigned* __restrict__ perm2,
                                            const float* __restrict__ hs1,
                                            const float* __restrict__ dinv,
                                            const float* __restrict__ W2,
                                            const float* __restrict__ b1,
                                            float* __restrict__ hs2) {
  int node = blockIdx.x * 16 + (threadIdx.x >> 4);
  int l = threadIdx.x & 15;
  int2 od = offdeg[node];
  int base = od.x, d = od.y;
  float a0 = 0, a1 = 0, a2 = 0, a3 = 0;
  for (int j = 4 * l; j + 4 <= d; j += 64) {
    uint4 s = *(const uint4*)(perm2 + base + j);
    float4 v0 = ((const float4*)hs1)[s.x];
    float4 v1 = ((const float4*)hs1)[s.y];
    float4 v2 = ((const float4*)hs1)[s.z];
    float4 v3 = ((const float4*)hs1)[s.w];
    a0 += v0.x + v1.x + v2.x + v3.x;
    a1 += v0.y + v1.y + v2.y + v3.y;
    a2 += v0.z + v1.z + v2.z + v3.z;
    a3 += v0.w + v1.w + v2.w + v3.w;
  }
  int rb = d & ~3;
  if (l < d - rb) {
    float4 v = ((const float4*)hs1)[perm2[base + rb + l]];
    a0 += v.x; a1 += v.y; a2 += v.z; a3 += v.w;
  }
#pragma unroll
  for (int o = 8; o > 0; o >>= 1) {
    a0 += __shfl_down(a0, o); a1 += __shfl_down(a1, o);
    a2 += __shfl_down(a2, o); a3 += __shfl_down(a3, o);
  }
  if (l == 0) {
    float dn = dinv[node];
    float4 hl = ((const float4*)hs1)[node];
    float t0 = tanhf(dn * (a0 + hl.x) + b1[0]);
    float t1 = tanhf(dn * (a1 + hl.y) + b1[1]);
    float t2 = tanhf(dn * (a2 + hl.z) + b1[2]);
    float t3 = tanhf(dn * (a3 + hl.w) + b1[3]);
    float4 r;
    r.x = dn * (t0 * W2[0] + t1 * W2[4] + t2 * W2[8]  + t3 * W2[12]);
    r.y = dn * (t0 * W2[1] + t1 * W2[5] + t2 * W2[9]  + t3 * W2[13]);
    r.z = dn * (t0 * W2[2] + t1 * W2[6] + t2 * W2[10] + t3 * W2[14]);
    r.w = dn * (t0 * W2[3] + t1 * W2[7] + t2 * W2[11] + t3 * W2[15]);
    ((float4*)hs2)[node] = r;
  }
}

__global__ __launch_bounds__(256) void k_l2(const int2* __restrict__ offdeg,
                                            const unsigned* __restrict__ perm2,
                                            const float* __restrict__ hs2,
                                            const float* __restrict__ dinv,
                                            const float* __restrict__ W3,
                                            const float* __restrict__ b2,
                                            float* __restrict__ hs3) {
  int node = blockIdx.x * 16 + (threadIdx.x >> 4);
  int l = threadIdx.x & 15;
  int2 od = offdeg[node];
  int base = od.x, d = od.y;
  float a0 = 0, a1 = 0, a2 = 0, a3 = 0;
  for (int j = 4 * l; j + 4 <= d; j += 64) {
    uint4 s = *(const uint4*)(perm2 + base + j);
    float4 v0 = ((const float4*)hs2)[s.x];
    float4 v1 = ((const float4*)hs2)[s.y];
    float4 v2 = ((const float4*)hs2)[s.z];
    float4 v3 = ((const float4*)hs2)[s.w];
    a0 += v0.x + v1.x + v2.x + v3.x;
    a1 += v0.y + v1.y + v2.y + v3.y;
    a2 += v0.z + v1.z + v2.z + v3.z;
    a3 += v0.w + v1.w + v2.w + v3.w;
  }
  int rb = d & ~3;
  if (l < d - rb) {
    float4 v = ((const float4*)hs2)[perm2[base + rb + l]];
    a0 += v.x; a1 += v.y; a2 += v.z; a3 += v.w;
  }
#pragma unroll
  for (int o = 8; o > 0; o >>= 1) {
    a0 += __shfl_down(a0, o); a1 += __shfl_down(a1, o);
    a2 += __shfl_down(a2, o); a3 += __shfl_down(a3, o);
  }
  if (l == 0) {
    float dn = dinv[node];
    float4 hl = ((const float4*)hs2)[node];
    float t0 = tanhf(dn * (a0 + hl.x) + b2[0]);
    float t1 = tanhf(dn * (a1 + hl.y) + b2[1]);
    float t2 = tanhf(dn * (a2 + hl.z) + b2[2]);
    float t3 = tanhf(dn * (a3 + hl.w) + b2[3]);
    float2 r;
    r.x = dn * (t0 * W3[0] + t1 * W3[2] + t2 * W3[4] + t3 * W3[6]);
    r.y = dn * (t0 * W3[1] + t1 * W3[3] + t2 * W3[5] + t3 * W3[7]);
    ((float2*)hs3)[node] = r;
  }
}

__global__ __launch_bounds__(256) void k_l3(const int2* __restrict__ offdeg,
                                            const unsigned* __restrict__ perm2,
                                            const float* __restrict__ hs3,
                                            const float* __restrict__ dinv,
                                            const float* __restrict__ Wc,
                                            const float* __restrict__ bc,
                                            const float* __restrict__ b3,
                                            float* __restrict__ out) {
  int node = blockIdx.x * 16 + (threadIdx.x >> 4);
  int l = threadIdx.x & 15;
  int2 od = offdeg[node];
  int base = od.x, d = od.y;
  float a0 = 0, a1 = 0;
  for (int j = 4 * l; j + 4 <= d; j += 64) {
    uint4 s = *(const uint4*)(perm2 + base + j);
    float2 v0 = ((const float2*)hs3)[s.x];
    float2 v1 = ((const float2*)hs3)[s.y];
    float2 v2 = ((const float2*)hs3)[s.z];
    float2 v3 = ((const float2*)hs3)[s.w];
    a0 += v0.x + v1.x + v2.x + v3.x;
    a1 += v0.y + v1.y + v2.y + v3.y;
  }
  int rb = d & ~3;
  if (l < d - rb) {
    float2 v = ((const float2*)hs3)[perm2[base + rb + l]];
    a0 += v.x; a1 += v.y;
  }
  // butterfly: all 16 lanes end with the full sums (xor 8/4/2/1 stays in-group)
#pragma unroll
  for (int o = 8; o > 0; o >>= 1) {
    a0 += __shfl_xor(a0, o); a1 += __shfl_xor(a1, o);
  }
  float dn = dinv[node];
  float2 hl = ((const float2*)hs3)[node];
  float t0 = tanhf(dn * (a0 + hl.x) + b3[0]);
  float t1 = tanhf(dn * (a1 + hl.y) + b3[1]);
  // coalesced epilogue: 10 adjacent lanes write one class each (40B/node),
  // lanes 10/11 write the two h values
  if (l < 10)
    out[(size_t)node * 10 + l] = t0 * Wc[l] + t1 * Wc[10 + l] + bc[l];
  else if (l == 10)
    out[(size_t)N_NODES * 10 + 2 * node + 0] = t0;
  else if (l == 11)
    out[(size_t)N_NODES * 10 + 2 * node + 1] = t1;
}

// ---------------------------------------------------------------------------
extern "C" void kernel_launch(void* const* d_in, const int* in_sizes, int n_in,
                              void* d_out, int out_size, void* d_ws, size_t ws_size,
                              hipStream_t stream) {
  const float* x  = (const float*)d_in[0];
  const void*  ei = d_in[1];
  const float* W1 = (const float*)d_in[2];
  const float* b1 = (const float*)d_in[3];
  const float* W2 = (const float*)d_in[4];
  const float* b2 = (const float*)d_in[5];
  const float* W3 = (const float*)d_in[6];
  const float* b3 = (const float*)d_in[7];
  const float* Wc = (const float*)d_in[8];
  const float* bc = (const float*)d_in[9];
  float* out = (float*)d_out;

  const size_t N = N_NODES;
  float* base = (float*)d_ws;
  float* dinv = base;                            // N
  float* hs1  = base + N;                        // 4N
  float* hs2  = base + 5 * N;                    // 4N
  float* hs3  = base + 9 * N;                    // 2N
  int2*  offdeg = (int2*)(base + 11 * N);        // N int2 = 2N
  int*   gcur = (int*)(base + 13 * N);           // 1024
  unsigned* perm1 = (unsigned*)(base + 13 * N + 2048);   // NBKT*CAP (33.6 MB)
  unsigned* perm2 = perm1 + (size_t)NBKT * CAP;          // NBKT*CAP (33.6 MB)

  hipMemsetAsync(gcur, 0, 1024 * sizeof(int), stream);
  k_bin<<<NBIN_BLOCKS, BIN_THREADS, 0, stream>>>(ei, gcur, perm1);
  k_sort<<<NBKT, SORT_THREADS, 0, stream>>>(gcur, perm1, perm2, offdeg, dinv);
  k_mm1<<<(N_NODES * 64) / 256, 256, 0, stream>>>(x, W1, dinv, hs1);

  const int LB = N_NODES / 16;  // 6250
  k_l1<<<LB, 256, 0, stream>>>(offdeg, perm2, hs1, dinv, W2, b1, hs2);
  k_l2<<<LB, 256, 0, stream>>>(offdeg, perm2, hs2, dinv, W3, b2, hs3);
  k_l3<<<LB, 256, 0, stream>>>(offdeg, perm2, hs3, dinv, Wc, bc, b3, out);
}